// Round 1
// 296.854 us; speedup vs baseline: 1.0040x; 1.0040x over previous
//
#include <hip/hip_runtime.h>
#include <cstdint>
#include <cstddef>

// Problem constants
constexpr int Bc = 4;
constexpr int Tc = 4096;
constexpr int Cc = 1024;
constexpr int Hc = 16;
constexpr int Dc = 64;
constexpr int Mc = Bc * Tc;        // 16384 rows
constexpr int N1c = 3 * Cc;        // 3072
constexpr int Kc = Cc;             // 1024
constexpr int KBc = Kc / 32;       // 32 k-tiles

typedef __bf16 bf16x8 __attribute__((ext_vector_type(8)));
typedef float  f32x4  __attribute__((ext_vector_type(4)));
typedef __attribute__((address_space(1))) uint32_t gu32;
typedef __attribute__((address_space(3))) uint32_t lu32;

__device__ __forceinline__ float bf2f(unsigned short u) {
    return __uint_as_float(((unsigned)u) << 16);
}
__device__ __forceinline__ unsigned short f2bf(float f) {
    unsigned u = __float_as_uint(f);
    u += 0x7FFF + ((u >> 16) & 1);   // round-to-nearest-even (finite values)
    return (unsigned short)(u >> 16);
}

__device__ __forceinline__ void load_lds16(const void* g, void* l) {
    // wave-uniform LDS base + lane*16; per-lane global address
    __builtin_amdgcn_global_load_lds((gu32*)(uintptr_t)g, (lu32*)(uintptr_t)l, 16, 0, 0);
}

// ============ packed-fragment layout ============
// A 16(rows)x32(k) tile = 512 bf16 = 64 lanes x 8 elems, contiguous in lane order.
// lane = fq*16 + fr  (fr = row&15, fq = (k&31)>>3), elem j = k&7.
// tile index: (row>>4)*KB + (k>>5). Wave fragment load = tile_base + lane*16B
// -> one coalesced b128 (global) or one conflict-free ds_read_b128 (LDS).

// ---------------- x fp32 [M][K] -> packed bf16 fragments ----------------
__global__ void convert_x_packed(const float* __restrict__ x,
                                 unsigned short* __restrict__ Ap) {
    const int w = threadIdx.x >> 6, lane = threadIdx.x & 63;
    const int t = blockIdx.x * 4 + w;          // tile id = mb*KB + kb
    const int mb = t >> 5, kb = t & 31;
    const int r = lane >> 2, c = lane & 3;
    const float* src = x + (size_t)(mb * 16 + r) * Kc + kb * 32 + c * 8;
    float4 f0 = *(const float4*)src;
    float4 f1 = *(const float4*)(src + 4);
    unsigned short u[8];
    u[0] = f2bf(f0.x); u[1] = f2bf(f0.y); u[2] = f2bf(f0.z); u[3] = f2bf(f0.w);
    u[4] = f2bf(f1.x); u[5] = f2bf(f1.y); u[6] = f2bf(f1.z); u[7] = f2bf(f1.w);
    *(uint4*)(Ap + (size_t)t * 512 + (c * 16 + r) * 8) = *(uint4*)u;
}

// ---------------- W fp32 [K][N] -> packed bf16 fragments (transposed) ----------------
__global__ void transpose_convert_packed(const float* __restrict__ W,
                                         unsigned short* __restrict__ Bp,
                                         int K, int N) {
    __shared__ float tile[32][33];
    const int tx = threadIdx.x, ty = threadIdx.y;
    const int n0 = blockIdx.x * 32, k0 = blockIdx.y * 32;
    for (int i = ty; i < 32; i += 8)
        tile[i][tx] = W[(size_t)(k0 + i) * N + n0 + tx];
    __syncthreads();
    const int t = ty * 32 + tx;
    const int h = t >> 7, rr = t & 127, lane = rr >> 1, half = rr & 1;
    const int fq = lane >> 4, fn = lane & 15;
    unsigned short u[4];
    #pragma unroll
    for (int j = 0; j < 4; ++j)
        u[j] = f2bf(tile[fq * 8 + half * 4 + j][h * 16 + fn]);
    size_t tileIdx = (size_t)((n0 >> 4) + h) * (K >> 5) + (k0 >> 5);
    *(uint2*)(Bp + tileIdx * 512 + lane * 8 + half * 4) = *(uint2*)u;
}

// ---------------- 256x256 8-wave phase-interleaved bf16 MFMA GEMM ----------------
// T3+T4+T5 on the packed-fragment layout (layout already gives T2's zero
// bank conflicts). BK=32 (one packed k-tile per K-step), double-buffered
// LDS = 64 KB, 512 threads = 8 waves in a 2(M)x4(N) grid, 128x64 per wave.
//
// Per K-step k (buffer c = k&1):
//  phase0: ds_read B(4 tiles) + A-half0(4); issue LATE pair of L(k+1) into
//          buf c^1 (idle); 16 MFMA (setprio-wrapped); s_barrier.
//  phase1: ds_read A-half1(4); issue EARLY pair of L(k+2) into buf c,
//          targeting ONLY regions consumed at phase0 (G0 waves own half0
//          A-tiles, G1 waves own B-tiles -> provably race-free);
//          16 MFMA; s_waitcnt vmcnt(2) (never 0 mid-loop); s_barrier.
// Counted vmcnt: the 2 newest in-flight loads are always L(k+2)'s early
// pair; waiting to depth 2 guarantees L(k+1) has landed.
template <bool OUT_BF16>
__global__ __launch_bounds__(512, 2) void gemm8p_kernel(
    const unsigned short* __restrict__ Ap,
    const unsigned short* __restrict__ Bp,
    const float* __restrict__ bias,
    void* __restrict__ Cout,
    int M, int N, int K, int NBLK) {
    __shared__ unsigned short sA[2][16][512];   // [buf][local mtile][frag]
    __shared__ unsigned short sB[2][16][512];   // [buf][local ntile][frag]
    const int KB = K >> 5;

    // XCD-aware swizzle (grid % 8 == 0 for both GEMMs)
    const int id  = blockIdx.x;
    const int xcd = id & 7;
    const int per = id >> 3;
    const int by  = xcd * ((M >> 8) >> 3) + per / NBLK;
    const int bx  = per % NBLK;

    const int w    = threadIdx.x >> 6;
    const int lane = threadIdx.x & 63;
    const int am   = (w >> 2) * 8;       // A local mtile base (0 or 8)
    const int bn   = (w & 3) * 4;        // B local ntile base
    const int la0  = 2 * w, la1 = 2 * w + 1;    // tiles this wave stages
    const bool earlyA = ((w & 2) == 0);  // G0: A-tiles are in half0 -> early-safe

    // per-lane global fragment pointers (tile base + lane*16B)
    const unsigned short* gA0 = Ap + ((size_t)(by * 16 + la0) * KB) * 512 + lane * 8;
    const unsigned short* gA1 = Ap + ((size_t)(by * 16 + la1) * KB) * 512 + lane * 8;
    const unsigned short* gB0 = Bp + ((size_t)(bx * 16 + la0) * KB) * 512 + lane * 8;
    const unsigned short* gB1 = Bp + ((size_t)(bx * 16 + la1) * KB) * 512 + lane * 8;

    // early pair = region consumed in phase0; late pair = the other one
    const unsigned short* gE0 = earlyA ? gA0 : gB0;
    const unsigned short* gE1 = earlyA ? gA1 : gB1;
    const unsigned short* gL0 = earlyA ? gB0 : gA0;
    const unsigned short* gL1 = earlyA ? gB1 : gA1;
    unsigned short* const dE0_0 = earlyA ? &sA[0][la0][0] : &sB[0][la0][0];
    unsigned short* const dE1_0 = earlyA ? &sA[0][la1][0] : &sB[0][la1][0];
    unsigned short* const dE0_1 = earlyA ? &sA[1][la0][0] : &sB[1][la0][0];
    unsigned short* const dE1_1 = earlyA ? &sA[1][la1][0] : &sB[1][la1][0];
    unsigned short* const dL0_0 = earlyA ? &sB[0][la0][0] : &sA[0][la0][0];
    unsigned short* const dL1_0 = earlyA ? &sB[0][la1][0] : &sA[0][la1][0];
    unsigned short* const dL0_1 = earlyA ? &sB[1][la0][0] : &sA[1][la0][0];
    unsigned short* const dL1_1 = earlyA ? &sB[1][la1][0] : &sA[1][la1][0];

    // prologue: L_0 complete (4 loads, buf0) + early pair of L_1 (buf1)
    load_lds16(gA0, &sA[0][la0][0]);
    load_lds16(gA1, &sA[0][la1][0]);
    load_lds16(gB0, &sB[0][la0][0]);
    load_lds16(gB1, &sB[0][la1][0]);
    load_lds16(gE0 + 512, dE0_1);
    load_lds16(gE1 + 512, dE1_1);

    const f32x4 zero4 = {0.f, 0.f, 0.f, 0.f};
    f32x4 acc[8][4];
    #pragma unroll
    for (int i = 0; i < 8; ++i)
        #pragma unroll
        for (int j = 0; j < 4; ++j) acc[i][j] = zero4;

    asm volatile("s_waitcnt vmcnt(2)" ::: "memory");   // L_0 landed
    __builtin_amdgcn_s_barrier();

    #pragma unroll 2
    for (int k = 0; k < KB; ++k) {
        const int c = k & 1;
        const unsigned short* sAc = &sA[c][0][0];
        const unsigned short* sBc = &sB[c][0][0];
        bf16x8 af[4], bfr[4];

        // ---- phase 0 ----
        #pragma unroll
        for (int ni = 0; ni < 4; ++ni)
            bfr[ni] = *(const bf16x8*)(sBc + (bn + ni) * 512 + lane * 8);
        #pragma unroll
        for (int mi = 0; mi < 4; ++mi)
            af[mi] = *(const bf16x8*)(sAc + (am + mi) * 512 + lane * 8);
        if (k + 1 < KB) {   // late pair of L(k+1) -> idle buffer c^1
            const size_t o = (size_t)(k + 1) * 512;
            load_lds16(gL0 + o, c ? dL0_0 : dL0_1);
            load_lds16(gL1 + o, c ? dL1_0 : dL1_1);
        }
        __builtin_amdgcn_s_setprio(1);
        #pragma unroll
        for (int mi = 0; mi < 4; ++mi)
            #pragma unroll
            for (int ni = 0; ni < 4; ++ni)
                acc[mi][ni] = __builtin_amdgcn_mfma_f32_16x16x32_bf16(
                    af[mi], bfr[ni], acc[mi][ni], 0, 0, 0);
        __builtin_amdgcn_s_setprio(0);
        __builtin_amdgcn_s_barrier();

        // ---- phase 1 ----
        #pragma unroll
        for (int mi = 0; mi < 4; ++mi)
            af[mi] = *(const bf16x8*)(sAc + (am + 4 + mi) * 512 + lane * 8);
        if (k + 2 < KB) {   // early pair of L(k+2) -> buf c, phase0-consumed regions
            const size_t o = (size_t)(k + 2) * 512;
            load_lds16(gE0 + o, c ? dE0_1 : dE0_0);
            load_lds16(gE1 + o, c ? dE1_1 : dE1_0);
        }
        __builtin_amdgcn_s_setprio(1);
        #pragma unroll
        for (int mi = 0; mi < 4; ++mi)
            #pragma unroll
            for (int ni = 0; ni < 4; ++ni)
                acc[4 + mi][ni] = __builtin_amdgcn_mfma_f32_16x16x32_bf16(
                    af[mi], bfr[ni], acc[4 + mi][ni], 0, 0, 0);
        __builtin_amdgcn_s_setprio(0);
        if (k + 2 < KB)
            asm volatile("s_waitcnt vmcnt(2)" ::: "memory");  // L(k+1) landed
        else
            asm volatile("s_waitcnt vmcnt(0)" ::: "memory");  // tail drain
        __builtin_amdgcn_s_barrier();
    }

    // epilogue: D row = (lane>>4)*4 + reg, col = lane&15
    const int fr = lane & 15;
    const int fq = lane >> 4;
    const int m0 = by * 256 + (w >> 2) * 128;
    const int n0 = bx * 256 + (w & 3) * 64;
    #pragma unroll
    for (int mi = 0; mi < 8; ++mi) {
        #pragma unroll
        for (int ni = 0; ni < 4; ++ni) {
            int row = m0 + mi * 16 + fq * 4;
            int col = n0 + ni * 16 + fr;
            float bb = bias[col];
            #pragma unroll
            for (int r = 0; r < 4; ++r) {
                float v = acc[mi][ni][r] + bb;
                if (OUT_BF16)
                    ((unsigned short*)Cout)[(size_t)(row + r) * N + col] = f2bf(v);
                else
                    ((float*)Cout)[(size_t)(row + r) * N + col] = v;
            }
        }
    }
}

// ---------------- per-token head-axis attention, MFMA, packed-fragment out ----------------
// One wave per token; output written directly in packed-fragment layout so it
// feeds gemm8p as A (no repack pass).
__global__ __launch_bounds__(256) void attn_mfma_kernel(
    const unsigned short* __restrict__ qkv,
    unsigned short* __restrict__ attP) {
    __shared__ char smem[4 * 3584];
    const int w    = threadIdx.x >> 6;
    const int lane = threadIdx.x & 63;
    const int m    = lane & 15;
    const int q    = lane >> 4;
    const int row  = blockIdx.x * 4 + w;
    unsigned short* sV = (unsigned short*)(smem + w * 3584);        // [16][72] bf16
    float*          sP = (float*)(smem + w * 3584 + 2304);          // [16][20] fp32

    const unsigned short* src = qkv + (size_t)row * 3072;

    bf16x8 aq0 = *(const bf16x8*)(src + m * 64 + q * 8);
    bf16x8 aq1 = *(const bf16x8*)(src + m * 64 + 32 + q * 8);
    bf16x8 bk0 = *(const bf16x8*)(src + 1024 + m * 64 + q * 8);
    bf16x8 bk1 = *(const bf16x8*)(src + 1024 + m * 64 + 32 + q * 8);

    #pragma unroll
    for (int t = 0; t < 2; ++t) {
        int G = t * 64 + lane;
        int r = G >> 3, p = G & 7;
        *(uint4*)(sV + r * 72 + p * 8) = *(const uint4*)(src + 2048 + G * 8);
    }

    f32x4 s = {0.f, 0.f, 0.f, 0.f};
    s = __builtin_amdgcn_mfma_f32_16x16x32_bf16(aq0, bk0, s, 0, 0, 0);
    s = __builtin_amdgcn_mfma_f32_16x16x32_bf16(aq1, bk1, s, 0, 0, 0);

    #pragma unroll
    for (int r = 0; r < 4; ++r) {
        float t0 = s[r] * 0.125f;
        float mx = t0;
        mx = fmaxf(mx, __shfl_xor(mx, 1));
        mx = fmaxf(mx, __shfl_xor(mx, 2));
        mx = fmaxf(mx, __shfl_xor(mx, 4));
        mx = fmaxf(mx, __shfl_xor(mx, 8));
        float e = __expf(t0 - mx);
        float su = e;
        su += __shfl_xor(su, 1);
        su += __shfl_xor(su, 2);
        su += __shfl_xor(su, 4);
        su += __shfl_xor(su, 8);
        sP[(q * 4 + r) * 20 + m] = e / su;
    }
    __syncthreads();

    const float* pr = sP + m * 20 + (q & 1) * 8;
    float4 pf0 = *(const float4*)(pr);
    float4 pf1 = *(const float4*)(pr + 4);
    const bool act = (q < 2);
    union { unsigned short u[8]; bf16x8 b; } pa;
    pa.u[0] = act ? f2bf(pf0.x) : 0;
    pa.u[1] = act ? f2bf(pf0.y) : 0;
    pa.u[2] = act ? f2bf(pf0.z) : 0;
    pa.u[3] = act ? f2bf(pf0.w) : 0;
    pa.u[4] = act ? f2bf(pf1.x) : 0;
    pa.u[5] = act ? f2bf(pf1.y) : 0;
    pa.u[6] = act ? f2bf(pf1.z) : 0;
    pa.u[7] = act ? f2bf(pf1.w) : 0;

    const unsigned short* vb = sV + (q & 1) * 8 * 72;
    const size_t tileBase = (size_t)(row >> 4) * 32 * 512;   // token's m-block row (KB=32)
    const int fr_tok = row & 15;
    #pragma unroll
    for (int c4 = 0; c4 < 4; ++c4) {
        union { unsigned short u[8]; bf16x8 b; } vf;
        #pragma unroll
        for (int j = 0; j < 8; ++j) vf.u[j] = vb[j * 72 + c4 * 16 + m];
        f32x4 o = {0.f, 0.f, 0.f, 0.f};
        o = __builtin_amdgcn_mfma_f32_16x16x32_bf16(pa.b, vf.b, o, 0, 0, 0);
        #pragma unroll
        for (int r = 0; r < 4; ++r) {
            int col = (q * 4 + r) * 64 + c4 * 16 + m;        // k index in [0,1024)
            size_t off = tileBase + (size_t)(col >> 5) * 512
                       + (((col >> 3) & 3) * 16 + fr_tok) * 8 + (col & 7);
            attP[off] = f2bf(o[r]);
        }
    }
}

extern "C" void kernel_launch(void* const* d_in, const int* in_sizes, int n_in,
                              void* d_out, int out_size, void* d_ws, size_t ws_size,
                              hipStream_t stream) {
    const float* x    = (const float*)d_in[0];
    const float* Wqkv = (const float*)d_in[1];
    const float* bqkv = (const float*)d_in[2];
    const float* Wout = (const float*)d_in[3];
    const float* bout = (const float*)d_in[4];
    float* out = (float*)d_out;

    // workspace: xp 32M | Wqkv_p 6M | Wout_p 2M | qkv 96M = ~136 MB
    char* ws = (char*)d_ws;
    unsigned short* xp   = (unsigned short*)ws;                 ws += (size_t)Mc * Kc * 2;
    unsigned short* Wqkp = (unsigned short*)ws;                 ws += (size_t)N1c * Kc * 2;
    unsigned short* Wop  = (unsigned short*)ws;                 ws += (size_t)Cc * Kc * 2;
    unsigned short* qkv  = (unsigned short*)ws;
    unsigned short* attP = xp;   // alias: xp dead after GEMM1

    // 1) x -> packed bf16 fragments
    convert_x_packed<<<(Mc / 16) * KBc / 4, 256, 0, stream>>>(x, xp);
    // 2) weights -> packed bf16 fragments (transposed)
    transpose_convert_packed<<<dim3(N1c / 32, Kc / 32), dim3(32, 8), 0, stream>>>(Wqkv, Wqkp, Kc, N1c);
    transpose_convert_packed<<<dim3(Cc / 32, Kc / 32), dim3(32, 8), 0, stream>>>(Wout, Wop, Kc, Cc);
    // 3) qkv = x @ W_qkv + b_qkv   (bf16 row-major out), 256^2 tiles: 64x12 blocks
    gemm8p_kernel<true><<<(Mc / 256) * (N1c / 256) * 1, 512, 0, stream>>>(
        xp, Wqkp, bqkv, qkv, Mc, N1c, Kc, N1c / 256);
    // 4) head-axis attention per token (MFMA), writes packed-fragment A
    attn_mfma_kernel<<<Mc / 4, 256, 0, stream>>>(qkv, attP);
    // 5) out = att @ W_out + b_out (fp32 row-major out), 64x4 blocks
    gemm8p_kernel<false><<<(Mc / 256) * (Cc / 256) * 1, 512, 0, stream>>>(
        attP, Wop, bout, out, Mc, Cc, Kc, Cc / 256);
}